// Round 1
// baseline (71.156 us; speedup 1.0000x reference)
//
#include <hip/hip_runtime.h>
#include <math.h>

#define RR 32
#define R3 (RR*RR*RR)
#define BATCH 8
#define NPTS 32768
#define CCH 64

static constexpr int ABLK = 32;   // stats blocks per batch
static constexpr int FBLK = 64;   // feature blocks per batch (4 waves each)

// ---------------- Kernel A: per-batch per-component sum of squares (partial) ----------------
__global__ __launch_bounds__(256) void stats_kernel(const float* __restrict__ coords,
                                                    double* __restrict__ partials) {
    int b = blockIdx.y;
    int tid = threadIdx.x;
    double sx = 0.0, sy = 0.0, sz = 0.0;
    for (int n = blockIdx.x * 256 + tid; n < NPTS; n += ABLK * 256) {
        const float* p = coords + ((size_t)b * NPTS + n) * 3;
        float x = p[0], y = p[1], z = p[2];
        float m = (x + y + z) / 3.0f;
        float dx = x - m, dy = y - m, dz = z - m;
        sx += (double)dx * (double)dx;
        sy += (double)dy * (double)dy;
        sz += (double)dz * (double)dz;
    }
    __shared__ double s0[256], s1[256], s2[256];
    s0[tid] = sx; s1[tid] = sy; s2[tid] = sz;
    __syncthreads();
    for (int off = 128; off > 0; off >>= 1) {
        if (tid < off) {
            s0[tid] += s0[tid + off];
            s1[tid] += s1[tid + off];
            s2[tid] += s2[tid + off];
        }
        __syncthreads();
    }
    if (tid == 0) {
        double* o = partials + ((size_t)b * ABLK + blockIdx.x) * 3;
        o[0] = s0[0]; o[1] = s1[0]; o[2] = s2[0];
    }
}

// ---------------- Kernel B: final reduce -> denom per batch ----------------
__global__ __launch_bounds__(64) void denom_kernel(const double* __restrict__ partials,
                                                   float* __restrict__ denom) {
    __shared__ double nrm[BATCH][3];
    int t = threadIdx.x;
    if (t < BATCH * 3) {
        int b = t / 3, c = t - b * 3;
        double s = 0.0;
        for (int i = 0; i < ABLK; ++i) s += partials[((size_t)b * ABLK + i) * 3 + c];
        nrm[b][c] = sqrt(s);
    }
    __syncthreads();
    if (t < BATCH) {
        double mx = fmax(fmax(nrm[t][0], nrm[t][1]), nrm[t][2]);
        denom[t] = (float)(mx * 2.0);
    }
}

// ---------------- Kernel C: per-point nc + voxel idx + counts ----------------
__global__ __launch_bounds__(256) void points_kernel(const float* __restrict__ coords,
                                                     const float* __restrict__ denom,
                                                     float* __restrict__ nc_out,
                                                     int* __restrict__ idx_out,
                                                     int* __restrict__ counts) {
    int gid = blockIdx.x * 256 + threadIdx.x;      // 0 .. B*NPTS-1
    int b = gid >> 15;                             // NPTS = 32768
    const float* p = coords + (size_t)gid * 3;
    float x = p[0], y = p[1], z = p[2];
    float m = (x + y + z) / 3.0f;
    float d = denom[b];
    float fx = (x - m) / d + 0.5f;
    float fy = (y - m) / d + 0.5f;
    float fz = (z - m) / d + 0.5f;
    float tx = fminf(fmaxf(fx * (float)RR, 0.0f), (float)(RR - 1));
    float ty = fminf(fmaxf(fy * (float)RR, 0.0f), (float)(RR - 1));
    float tz = fminf(fmaxf(fz * (float)RR, 0.0f), (float)(RR - 1));
    float* o = nc_out + (size_t)gid * 3;
    o[0] = tx; o[1] = ty; o[2] = tz;
    int vx = (int)rintf(tx), vy = (int)rintf(ty), vz = (int)rintf(tz);
    int v = vx * (RR * RR) + vy * RR + vz;
    idx_out[gid] = v;
    // wave-aggregated count atomic (voxel is ~always wave-uniform in this data)
    int first = __shfl(v, 0);
    if (__all(v == first)) {
        if ((threadIdx.x & 63) == 0) atomicAdd(&counts[b * R3 + v], 64);
    } else {
        atomicAdd(&counts[b * R3 + v], 1);
    }
}

// ---------------- Kernel F: feature scatter, lane = channel, run-length flush ----------------
__global__ __launch_bounds__(256) void feat_kernel(const float* __restrict__ features,
                                                   const int* __restrict__ idx,
                                                   const int* __restrict__ counts,
                                                   float* __restrict__ out) {
    int b = blockIdx.y;
    int wave = (blockIdx.x * 256 + threadIdx.x) >> 6;   // wave id within batch
    int lane = threadIdx.x & 63;                        // = channel
    constexpr int WPB = FBLK * 4;                       // waves per batch
    constexpr int PPW = NPTS / WPB;                     // points per wave
    const float* fbase = features + (size_t)b * NPTS * CCH;
    const int* ibase = idx + (size_t)b * NPTS;
    const int* cbase = counts + (size_t)b * R3;
    float* obase = out + (size_t)b * CCH * R3;
    int p0 = wave * PPW;
    int cur = -1;
    float acc = 0.0f;
    for (int i = 0; i < PPW; ++i) {
        int p = p0 + i;
        int v = ibase[p];                               // wave-uniform broadcast load
        float f = fbase[(size_t)p * CCH + lane];        // coalesced 256B row
        if (v != cur) {                                 // wave-uniform branch, rarely taken
            if (cur >= 0) {
                float cnt = (float)cbase[cur];
                atomicAdd(&obase[(size_t)lane * R3 + cur], acc / cnt);
            }
            cur = v;
            acc = 0.0f;
        }
        acc += f;
    }
    if (cur >= 0) {
        float cnt = (float)cbase[cur];
        atomicAdd(&obase[(size_t)lane * R3 + cur], acc / cnt);
    }
}

extern "C" void kernel_launch(void* const* d_in, const int* in_sizes, int n_in,
                              void* d_out, int out_size, void* d_ws, size_t ws_size,
                              hipStream_t stream) {
    const float* features = (const float*)d_in[0];
    const float* coords   = (const float*)d_in[1];
    float* out = (float*)d_out;

    float* voxf = out;                                    // (B, C, R, R, R)
    float* nc   = out + (size_t)BATCH * CCH * R3;         // (B, N, 3)

    char* ws = (char*)d_ws;
    int*    counts   = (int*)ws;                          // B*R3 ints = 1 MiB (zeroed)
    int*    idx      = (int*)(ws + (1 << 20));            // B*NPTS ints = 1 MiB
    double* partials = (double*)(ws + (2 << 20));         // B*ABLK*3 doubles = 6 KiB
    float*  denom    = (float*)(ws + (2 << 20) + 8192);   // B floats

    hipMemsetAsync(counts, 0, (size_t)BATCH * R3 * sizeof(int), stream);
    hipMemsetAsync(voxf, 0, (size_t)BATCH * CCH * R3 * sizeof(float), stream);

    dim3 agrid(ABLK, BATCH);
    stats_kernel<<<agrid, 256, 0, stream>>>(coords, partials);
    denom_kernel<<<1, 64, 0, stream>>>(partials, denom);

    int nblk = (BATCH * NPTS) / 256;
    points_kernel<<<nblk, 256, 0, stream>>>(coords, denom, nc, idx, counts);

    dim3 fgrid(FBLK, BATCH);
    feat_kernel<<<fgrid, 256, 0, stream>>>(features, idx, counts, voxf);
}

// Round 2
// 61.317 us; speedup vs baseline: 1.1605x; 1.1605x over previous
//
#include <hip/hip_runtime.h>
#include <math.h>

#define RR 32
#define R3 (RR*RR*RR)
#define BATCH 8
#define NPTS 32768
#define CCH 64

static constexpr int ABLK = 32;              // stats blocks per batch
static constexpr int WPB  = 512;             // feature waves per batch
static constexpr int PPW  = NPTS / WPB;      // points per wave (64)
static constexpr int FBLK = WPB / 4;         // feature blocks per batch (128)

// ---------------- Kernel A: per-batch per-component sum of squares (partial) ----------------
__global__ __launch_bounds__(256) void stats_kernel(const float* __restrict__ coords,
                                                    double* __restrict__ partials) {
    int b = blockIdx.y;
    int tid = threadIdx.x;
    double sx = 0.0, sy = 0.0, sz = 0.0;
    for (int n = blockIdx.x * 256 + tid; n < NPTS; n += ABLK * 256) {
        const float* p = coords + ((size_t)b * NPTS + n) * 3;
        float x = p[0], y = p[1], z = p[2];
        float m = (x + y + z) / 3.0f;
        float dx = x - m, dy = y - m, dz = z - m;
        sx += (double)dx * (double)dx;
        sy += (double)dy * (double)dy;
        sz += (double)dz * (double)dz;
    }
    __shared__ double s0[256], s1[256], s2[256];
    s0[tid] = sx; s1[tid] = sy; s2[tid] = sz;
    __syncthreads();
    for (int off = 128; off > 0; off >>= 1) {
        if (tid < off) {
            s0[tid] += s0[tid + off];
            s1[tid] += s1[tid + off];
            s2[tid] += s2[tid + off];
        }
        __syncthreads();
    }
    if (tid == 0) {
        double* o = partials + ((size_t)b * ABLK + blockIdx.x) * 3;
        o[0] = s0[0]; o[1] = s1[0]; o[2] = s2[0];
    }
}

// ---------------- Kernel B: final reduce -> denom per batch ----------------
__global__ __launch_bounds__(64) void denom_kernel(const double* __restrict__ partials,
                                                   float* __restrict__ denom) {
    __shared__ double nrm[BATCH][3];
    int t = threadIdx.x;
    if (t < BATCH * 3) {
        int b = t / 3, c = t - b * 3;
        double s = 0.0;
        for (int i = 0; i < ABLK; ++i) s += partials[((size_t)b * ABLK + i) * 3 + c];
        nrm[b][c] = sqrt(s);
    }
    __syncthreads();
    if (t < BATCH) {
        double mx = fmax(fmax(nrm[t][0], nrm[t][1]), nrm[t][2]);
        denom[t] = (float)(mx * 2.0);
    }
}

// ---------------- Kernel C: per-point nc + voxel idx + counts ----------------
__global__ __launch_bounds__(256) void points_kernel(const float* __restrict__ coords,
                                                     const float* __restrict__ denom,
                                                     float* __restrict__ nc_out,
                                                     int* __restrict__ idx_out,
                                                     int* __restrict__ counts) {
    int gid = blockIdx.x * 256 + threadIdx.x;      // 0 .. B*NPTS-1
    int b = gid >> 15;                             // NPTS = 32768
    const float* p = coords + (size_t)gid * 3;
    float x = p[0], y = p[1], z = p[2];
    float m = (x + y + z) / 3.0f;
    float d = denom[b];
    float fx = (x - m) / d + 0.5f;
    float fy = (y - m) / d + 0.5f;
    float fz = (z - m) / d + 0.5f;
    float tx = fminf(fmaxf(fx * (float)RR, 0.0f), (float)(RR - 1));
    float ty = fminf(fmaxf(fy * (float)RR, 0.0f), (float)(RR - 1));
    float tz = fminf(fmaxf(fz * (float)RR, 0.0f), (float)(RR - 1));
    float* o = nc_out + (size_t)gid * 3;
    o[0] = tx; o[1] = ty; o[2] = tz;
    int vx = (int)rintf(tx), vy = (int)rintf(ty), vz = (int)rintf(tz);
    int v = vx * (RR * RR) + vy * RR + vz;
    idx_out[gid] = v;
    // wave-aggregated count atomic (voxel is ~always wave-uniform in this data)
    int first = __shfl(v, 0);
    if (__all(v == first)) {
        if ((threadIdx.x & 63) == 0) atomicAdd(&counts[b * R3 + v], 64);
    } else {
        atomicAdd(&counts[b * R3 + v], 1);
    }
}

// ---------------- Kernel F: feature scatter ----------------
// Wave layout: lane = (sub, cslice); sub = lane>>4 picks one of 4 points per
// iteration, cslice = (lane&15)*4 picks 4 contiguous channels -> one float4.
// Per iteration the wave loads 4 points x 64 ch = 1 KB fully coalesced.
// Run-length accumulate on (wave-uniform) voxel id; on flush, reduce across
// the 4 point-subgroups via shfl_xor so only lanes 0..15 hit global atomics.
__global__ __launch_bounds__(256) void feat_kernel(const float* __restrict__ features,
                                                   const int* __restrict__ idx,
                                                   const int* __restrict__ counts,
                                                   float* __restrict__ out) {
    int b = blockIdx.y;
    int wave = (blockIdx.x * 256 + threadIdx.x) >> 6;   // wave id within batch
    int lane = threadIdx.x & 63;
    int sub = lane >> 4;                                // point sub-index 0..3
    int cb  = (lane & 15) << 2;                         // channel base 0..60
    const float* fbase = features + (size_t)b * NPTS * CCH;
    const int* ibase = idx + (size_t)b * NPTS;
    const int* cbase = counts + (size_t)b * R3;
    float* obase = out + (size_t)b * CCH * R3;
    int p0 = wave * PPW;

    int cur = -1;
    float ax = 0.f, ay = 0.f, az = 0.f, aw = 0.f;

    #pragma unroll 4
    for (int i = 0; i < PPW; i += 4) {
        int p = p0 + i + sub;
        int v = ibase[p];
        float4 f = *(const float4*)(fbase + (size_t)p * CCH + cb);
        if (!__all(v == cur)) {                         // wave-uniform
            if (cur >= 0) {
                float s = 1.0f / (float)cbase[cur];
                float fx_ = ax * s, fy_ = ay * s, fz_ = az * s, fw_ = aw * s;
                fx_ += __shfl_xor(fx_, 16); fx_ += __shfl_xor(fx_, 32);
                fy_ += __shfl_xor(fy_, 16); fy_ += __shfl_xor(fy_, 32);
                fz_ += __shfl_xor(fz_, 16); fz_ += __shfl_xor(fz_, 32);
                fw_ += __shfl_xor(fw_, 16); fw_ += __shfl_xor(fw_, 32);
                if (sub == 0) {
                    size_t o = (size_t)cb * R3 + cur;
                    atomicAdd(&obase[o],          fx_);
                    atomicAdd(&obase[o + R3],     fy_);
                    atomicAdd(&obase[o + 2*R3],   fz_);
                    atomicAdd(&obase[o + 3*R3],   fw_);
                }
                ax = ay = az = aw = 0.f;
                cur = -1;
            }
            int v0 = __shfl(v, 0);
            if (__all(v == v0)) {                       // wave-uniform
                cur = v0;
            } else {
                // mixed voxels within this 4-point group: direct per-lane atomics
                float s = 1.0f / (float)cbase[v];
                size_t o = (size_t)cb * R3 + v;
                atomicAdd(&obase[o],        f.x * s);
                atomicAdd(&obase[o + R3],   f.y * s);
                atomicAdd(&obase[o + 2*R3], f.z * s);
                atomicAdd(&obase[o + 3*R3], f.w * s);
                continue;
            }
        }
        ax += f.x; ay += f.y; az += f.z; aw += f.w;
    }
    if (cur >= 0) {
        float s = 1.0f / (float)cbase[cur];
        float fx_ = ax * s, fy_ = ay * s, fz_ = az * s, fw_ = aw * s;
        fx_ += __shfl_xor(fx_, 16); fx_ += __shfl_xor(fx_, 32);
        fy_ += __shfl_xor(fy_, 16); fy_ += __shfl_xor(fy_, 32);
        fz_ += __shfl_xor(fz_, 16); fz_ += __shfl_xor(fz_, 32);
        fw_ += __shfl_xor(fw_, 16); fw_ += __shfl_xor(fw_, 32);
        if (sub == 0) {
            size_t o = (size_t)cb * R3 + cur;
            atomicAdd(&obase[o],        fx_);
            atomicAdd(&obase[o + R3],   fy_);
            atomicAdd(&obase[o + 2*R3], fz_);
            atomicAdd(&obase[o + 3*R3], fw_);
        }
    }
}

extern "C" void kernel_launch(void* const* d_in, const int* in_sizes, int n_in,
                              void* d_out, int out_size, void* d_ws, size_t ws_size,
                              hipStream_t stream) {
    const float* features = (const float*)d_in[0];
    const float* coords   = (const float*)d_in[1];
    float* out = (float*)d_out;

    float* voxf = out;                                    // (B, C, R, R, R)
    float* nc   = out + (size_t)BATCH * CCH * R3;         // (B, N, 3)

    char* ws = (char*)d_ws;
    int*    counts   = (int*)ws;                          // B*R3 ints = 1 MiB (zeroed)
    int*    idx      = (int*)(ws + (1 << 20));            // B*NPTS ints = 1 MiB
    double* partials = (double*)(ws + (2 << 20));         // B*ABLK*3 doubles = 6 KiB
    float*  denom    = (float*)(ws + (2 << 20) + 8192);   // B floats

    hipMemsetAsync(counts, 0, (size_t)BATCH * R3 * sizeof(int), stream);
    hipMemsetAsync(voxf, 0, (size_t)BATCH * CCH * R3 * sizeof(float), stream);

    dim3 agrid(ABLK, BATCH);
    stats_kernel<<<agrid, 256, 0, stream>>>(coords, partials);
    denom_kernel<<<1, 64, 0, stream>>>(partials, denom);

    int nblk = (BATCH * NPTS) / 256;
    points_kernel<<<nblk, 256, 0, stream>>>(coords, denom, nc, idx, counts);

    dim3 fgrid(FBLK, BATCH);
    feat_kernel<<<fgrid, 256, 0, stream>>>(features, idx, counts, voxf);
}

// Round 3
// 57.412 us; speedup vs baseline: 1.2394x; 1.0680x over previous
//
#include <hip/hip_runtime.h>
#include <math.h>

#define RR 32
#define R3 (RR*RR*RR)
#define BATCH 8
#define NPTS 32768
#define CCH 64

static constexpr int ABLK = 32;              // stats blocks per batch
static constexpr int WPB  = 512;             // feature waves per batch
static constexpr int PPW  = NPTS / WPB;      // points per wave (64)
static constexpr int FBLK = WPB / 4;         // feature blocks per batch (128)

// ---------------- Kernel Z: vectorized zero-fill (voxf 64MB + counts 1MB) ----------------
__global__ __launch_bounds__(256) void fill_zero(float4* __restrict__ a, int n4a,
                                                 float4* __restrict__ b, int n4b) {
    int stride = gridDim.x * 256;
    float4 z = make_float4(0.f, 0.f, 0.f, 0.f);
    for (int k = blockIdx.x * 256 + threadIdx.x; k < n4a; k += stride) a[k] = z;
    for (int k = blockIdx.x * 256 + threadIdx.x; k < n4b; k += stride) b[k] = z;
}

// ---------------- Kernel A: per-batch per-component sum of squares (partial) ----------------
__global__ __launch_bounds__(256) void stats_kernel(const float* __restrict__ coords,
                                                    double* __restrict__ partials) {
    int b = blockIdx.y;
    int tid = threadIdx.x;
    double sx = 0.0, sy = 0.0, sz = 0.0;
    for (int n = blockIdx.x * 256 + tid; n < NPTS; n += ABLK * 256) {
        const float* p = coords + ((size_t)b * NPTS + n) * 3;
        float x = p[0], y = p[1], z = p[2];
        float m = (x + y + z) / 3.0f;
        float dx = x - m, dy = y - m, dz = z - m;
        sx += (double)dx * (double)dx;
        sy += (double)dy * (double)dy;
        sz += (double)dz * (double)dz;
    }
    __shared__ double s0[256], s1[256], s2[256];
    s0[tid] = sx; s1[tid] = sy; s2[tid] = sz;
    __syncthreads();
    for (int off = 128; off > 0; off >>= 1) {
        if (tid < off) {
            s0[tid] += s0[tid + off];
            s1[tid] += s1[tid + off];
            s2[tid] += s2[tid + off];
        }
        __syncthreads();
    }
    if (tid == 0) {
        double* o = partials + ((size_t)b * ABLK + blockIdx.x) * 3;
        o[0] = s0[0]; o[1] = s1[0]; o[2] = s2[0];
    }
}

// ---------------- Kernel B: final reduce -> denom per batch ----------------
__global__ __launch_bounds__(64) void denom_kernel(const double* __restrict__ partials,
                                                   float* __restrict__ denom) {
    __shared__ double nrm[BATCH][3];
    int t = threadIdx.x;
    if (t < BATCH * 3) {
        int b = t / 3, c = t - b * 3;
        double s = 0.0;
        for (int i = 0; i < ABLK; ++i) s += partials[((size_t)b * ABLK + i) * 3 + c];
        nrm[b][c] = sqrt(s);
    }
    __syncthreads();
    if (t < BATCH) {
        double mx = fmax(fmax(nrm[t][0], nrm[t][1]), nrm[t][2]);
        denom[t] = (float)(mx * 2.0);
    }
}

// ---------------- Kernel C: per-point nc + voxel idx + counts ----------------
__global__ __launch_bounds__(256) void points_kernel(const float* __restrict__ coords,
                                                     const float* __restrict__ denom,
                                                     float* __restrict__ nc_out,
                                                     int* __restrict__ idx_out,
                                                     int* __restrict__ counts) {
    int gid = blockIdx.x * 256 + threadIdx.x;      // 0 .. B*NPTS-1
    int b = gid >> 15;                             // NPTS = 32768
    const float* p = coords + (size_t)gid * 3;
    float x = p[0], y = p[1], z = p[2];
    float m = (x + y + z) / 3.0f;
    float d = denom[b];
    float fx = (x - m) / d + 0.5f;
    float fy = (y - m) / d + 0.5f;
    float fz = (z - m) / d + 0.5f;
    float tx = fminf(fmaxf(fx * (float)RR, 0.0f), (float)(RR - 1));
    float ty = fminf(fmaxf(fy * (float)RR, 0.0f), (float)(RR - 1));
    float tz = fminf(fmaxf(fz * (float)RR, 0.0f), (float)(RR - 1));
    float* o = nc_out + (size_t)gid * 3;
    o[0] = tx; o[1] = ty; o[2] = tz;
    int vx = (int)rintf(tx), vy = (int)rintf(ty), vz = (int)rintf(tz);
    int v = vx * (RR * RR) + vy * RR + vz;
    idx_out[gid] = v;
    // wave-aggregated count atomic (voxel is ~always wave-uniform in this data)
    int first = __shfl(v, 0);
    if (__all(v == first)) {
        if ((threadIdx.x & 63) == 0) atomicAdd(&counts[b * R3 + v], 64);
    } else {
        atomicAdd(&counts[b * R3 + v], 1);
    }
}

// ---------------- Kernel F: feature scatter ----------------
// Wave layout: lane = (sub, cslice); sub = lane>>4 picks one of 4 points per
// iteration, cslice = (lane&15)*4 picks 4 contiguous channels -> one float4.
// Per iteration the wave loads 4 points x 64 ch = 1 KB fully coalesced.
// Run-length accumulate on (wave-uniform) voxel id; on flush, reduce across
// the 4 point-subgroups via shfl_xor so only lanes 0..15 hit global atomics.
__global__ __launch_bounds__(256) void feat_kernel(const float* __restrict__ features,
                                                   const int* __restrict__ idx,
                                                   const int* __restrict__ counts,
                                                   float* __restrict__ out) {
    int b = blockIdx.y;
    int wave = (blockIdx.x * 256 + threadIdx.x) >> 6;   // wave id within batch
    int lane = threadIdx.x & 63;
    int sub = lane >> 4;                                // point sub-index 0..3
    int cb  = (lane & 15) << 2;                         // channel base 0..60
    const float* fbase = features + (size_t)b * NPTS * CCH;
    const int* ibase = idx + (size_t)b * NPTS;
    const int* cbase = counts + (size_t)b * R3;
    float* obase = out + (size_t)b * CCH * R3;
    int p0 = wave * PPW;

    int cur = -1;
    float ax = 0.f, ay = 0.f, az = 0.f, aw = 0.f;

    #pragma unroll 4
    for (int i = 0; i < PPW; i += 4) {
        int p = p0 + i + sub;
        int v = ibase[p];
        float4 f = *(const float4*)(fbase + (size_t)p * CCH + cb);
        if (!__all(v == cur)) {                         // wave-uniform
            if (cur >= 0) {
                float s = 1.0f / (float)cbase[cur];
                float fx_ = ax * s, fy_ = ay * s, fz_ = az * s, fw_ = aw * s;
                fx_ += __shfl_xor(fx_, 16); fx_ += __shfl_xor(fx_, 32);
                fy_ += __shfl_xor(fy_, 16); fy_ += __shfl_xor(fy_, 32);
                fz_ += __shfl_xor(fz_, 16); fz_ += __shfl_xor(fz_, 32);
                fw_ += __shfl_xor(fw_, 16); fw_ += __shfl_xor(fw_, 32);
                if (sub == 0) {
                    size_t o = (size_t)cb * R3 + cur;
                    atomicAdd(&obase[o],          fx_);
                    atomicAdd(&obase[o + R3],     fy_);
                    atomicAdd(&obase[o + 2*R3],   fz_);
                    atomicAdd(&obase[o + 3*R3],   fw_);
                }
                ax = ay = az = aw = 0.f;
                cur = -1;
            }
            int v0 = __shfl(v, 0);
            if (__all(v == v0)) {                       // wave-uniform
                cur = v0;
            } else {
                // mixed voxels within this 4-point group: direct per-lane atomics
                float s = 1.0f / (float)cbase[v];
                size_t o = (size_t)cb * R3 + v;
                atomicAdd(&obase[o],        f.x * s);
                atomicAdd(&obase[o + R3],   f.y * s);
                atomicAdd(&obase[o + 2*R3], f.z * s);
                atomicAdd(&obase[o + 3*R3], f.w * s);
                continue;
            }
        }
        ax += f.x; ay += f.y; az += f.z; aw += f.w;
    }
    if (cur >= 0) {
        float s = 1.0f / (float)cbase[cur];
        float fx_ = ax * s, fy_ = ay * s, fz_ = az * s, fw_ = aw * s;
        fx_ += __shfl_xor(fx_, 16); fx_ += __shfl_xor(fx_, 32);
        fy_ += __shfl_xor(fy_, 16); fy_ += __shfl_xor(fy_, 32);
        fz_ += __shfl_xor(fz_, 16); fz_ += __shfl_xor(fz_, 32);
        fw_ += __shfl_xor(fw_, 16); fw_ += __shfl_xor(fw_, 32);
        if (sub == 0) {
            size_t o = (size_t)cb * R3 + cur;
            atomicAdd(&obase[o],        fx_);
            atomicAdd(&obase[o + R3],   fy_);
            atomicAdd(&obase[o + 2*R3], fz_);
            atomicAdd(&obase[o + 3*R3], fw_);
        }
    }
}

extern "C" void kernel_launch(void* const* d_in, const int* in_sizes, int n_in,
                              void* d_out, int out_size, void* d_ws, size_t ws_size,
                              hipStream_t stream) {
    const float* features = (const float*)d_in[0];
    const float* coords   = (const float*)d_in[1];
    float* out = (float*)d_out;

    float* voxf = out;                                    // (B, C, R, R, R)
    float* nc   = out + (size_t)BATCH * CCH * R3;         // (B, N, 3)

    char* ws = (char*)d_ws;
    int*    counts   = (int*)ws;                          // B*R3 ints = 1 MiB (zeroed)
    int*    idx      = (int*)(ws + (1 << 20));            // B*NPTS ints = 1 MiB
    double* partials = (double*)(ws + (2 << 20));         // B*ABLK*3 doubles = 6 KiB
    float*  denom    = (float*)(ws + (2 << 20) + 8192);   // B floats

    int n4_voxf   = (int)((size_t)BATCH * CCH * R3 / 4);  // 4M float4
    int n4_counts = (int)((size_t)BATCH * R3 / 4);        // 64K float4
    fill_zero<<<2048, 256, 0, stream>>>((float4*)voxf, n4_voxf,
                                        (float4*)counts, n4_counts);

    dim3 agrid(ABLK, BATCH);
    stats_kernel<<<agrid, 256, 0, stream>>>(coords, partials);
    denom_kernel<<<1, 64, 0, stream>>>(partials, denom);

    int nblk = (BATCH * NPTS) / 256;
    points_kernel<<<nblk, 256, 0, stream>>>(coords, denom, nc, idx, counts);

    dim3 fgrid(FBLK, BATCH);
    feat_kernel<<<fgrid, 256, 0, stream>>>(features, idx, counts, voxf);
}

// Round 4
// 52.726 us; speedup vs baseline: 1.3495x; 1.0889x over previous
//
#include <hip/hip_runtime.h>
#include <math.h>

#define RR 32
#define R3 (RR*RR*RR)
#define BATCH 8
#define NPTS 32768
#define CCH 64

static constexpr int ABLK = 32;              // stats blocks per batch
static constexpr int CZB  = 8;               // counts-zero blocks per batch (fused into stats)
static constexpr int WPB  = 512;             // feature waves per batch
static constexpr int PPW  = NPTS / WPB;      // points per wave (64)
static constexpr int FBLK = WPB / 4;         // feature blocks per batch (128)
static constexpr int PBLK = BATCH * NPTS / 256;  // points blocks (1024)

// ---------------- Kernel A: per-batch per-component sum of squares (+ counts zero) ----------------
__global__ __launch_bounds__(256) void stats_kernel(const float* __restrict__ coords,
                                                    double* __restrict__ partials,
                                                    int* __restrict__ counts) {
    int b = blockIdx.y;
    int bx = blockIdx.x;
    int tid = threadIdx.x;
    if (bx >= ABLK) {
        // fused: zero this batch's counts slice (R3 ints = 128 KB)
        int zb = bx - ABLK;
        float4 z = make_float4(0.f, 0.f, 0.f, 0.f);
        float4* c4 = (float4*)(counts + (size_t)b * R3);
        for (int k = zb * 256 + tid; k < R3 / 4; k += CZB * 256) c4[k] = z;
        return;
    }
    double sx = 0.0, sy = 0.0, sz = 0.0;
    for (int n = bx * 256 + tid; n < NPTS; n += ABLK * 256) {
        const float* p = coords + ((size_t)b * NPTS + n) * 3;
        float x = p[0], y = p[1], z = p[2];
        float m = (x + y + z) / 3.0f;
        float dx = x - m, dy = y - m, dz = z - m;
        sx += (double)dx * (double)dx;
        sy += (double)dy * (double)dy;
        sz += (double)dz * (double)dz;
    }
    __shared__ double s0[256], s1[256], s2[256];
    s0[tid] = sx; s1[tid] = sy; s2[tid] = sz;
    __syncthreads();
    for (int off = 128; off > 0; off >>= 1) {
        if (tid < off) {
            s0[tid] += s0[tid + off];
            s1[tid] += s1[tid + off];
            s2[tid] += s2[tid + off];
        }
        __syncthreads();
    }
    if (tid == 0) {
        double* o = partials + ((size_t)b * ABLK + bx) * 3;
        o[0] = s0[0]; o[1] = s1[0]; o[2] = s2[0];
    }
}

// ---------------- Kernel B: final reduce -> denom per batch ----------------
__global__ __launch_bounds__(64) void denom_kernel(const double* __restrict__ partials,
                                                   float* __restrict__ denom) {
    __shared__ double nrm[BATCH][3];
    int t = threadIdx.x;
    if (t < BATCH * 3) {
        int b = t / 3, c = t - b * 3;
        double s = 0.0;
        for (int i = 0; i < ABLK; ++i) s += partials[((size_t)b * ABLK + i) * 3 + c];
        nrm[b][c] = sqrt(s);
    }
    __syncthreads();
    if (t < BATCH) {
        double mx = fmax(fmax(nrm[t][0], nrm[t][1]), nrm[t][2]);
        denom[t] = (float)(mx * 2.0);
    }
}

// ---------------- Kernel C: per-point nc + voxel idx + counts (+ voxf zero) ----------------
__global__ __launch_bounds__(256) void points_kernel(const float* __restrict__ coords,
                                                     const float* __restrict__ denom,
                                                     float* __restrict__ nc_out,
                                                     int* __restrict__ idx_out,
                                                     int* __restrict__ counts,
                                                     float* __restrict__ voxf) {
    int tid = threadIdx.x;
    // fused: zero a 64 KB contiguous slice of voxf (1024 blocks x 4096 float4)
    {
        float4 z = make_float4(0.f, 0.f, 0.f, 0.f);
        float4* o4 = (float4*)voxf + (size_t)blockIdx.x * 4096;
        #pragma unroll
        for (int k = 0; k < 16; ++k) o4[k * 256 + tid] = z;
    }
    int gid = blockIdx.x * 256 + tid;              // 0 .. B*NPTS-1
    int b = gid >> 15;                             // NPTS = 32768
    const float* p = coords + (size_t)gid * 3;
    float x = p[0], y = p[1], z = p[2];
    float m = (x + y + z) / 3.0f;
    float d = denom[b];
    float fx = (x - m) / d + 0.5f;
    float fy = (y - m) / d + 0.5f;
    float fz = (z - m) / d + 0.5f;
    float tx = fminf(fmaxf(fx * (float)RR, 0.0f), (float)(RR - 1));
    float ty = fminf(fmaxf(fy * (float)RR, 0.0f), (float)(RR - 1));
    float tz = fminf(fmaxf(fz * (float)RR, 0.0f), (float)(RR - 1));
    float* o = nc_out + (size_t)gid * 3;
    o[0] = tx; o[1] = ty; o[2] = tz;
    int vx = (int)rintf(tx), vy = (int)rintf(ty), vz = (int)rintf(tz);
    int v = vx * (RR * RR) + vy * RR + vz;
    idx_out[gid] = v;
    // wave-aggregated count atomic (voxel is ~always wave-uniform in this data)
    int first = __shfl(v, 0);
    if (__all(v == first)) {
        if ((tid & 63) == 0) atomicAdd(&counts[b * R3 + v], 64);
    } else {
        atomicAdd(&counts[b * R3 + v], 1);
    }
}

// ---------------- Kernel F: feature scatter, branch-free load phase ----------------
// Per wave: 64 points. lane = (sub, cslice): sub=lane>>4 -> point subgroup,
// cb=(lane&15)*4 -> 4 contiguous channels. All 16 float4 loads + 1 idx dword
// are issued before any control flow -> 4KB+ in flight per wave.
// Fast path (whole wave's 64 points share one voxel): 15 reg adds, shfl
// reduce across subs, lanes 0..15 flush 4 atomics each.
__global__ __launch_bounds__(256) void feat_kernel(const float* __restrict__ features,
                                                   const int* __restrict__ idx,
                                                   const int* __restrict__ counts,
                                                   float* __restrict__ out) {
    int b = blockIdx.y;
    int wave = (blockIdx.x * 256 + threadIdx.x) >> 6;   // wave id within batch
    int lane = threadIdx.x & 63;
    int sub = lane >> 4;                                // point sub-index 0..3
    int cb  = (lane & 15) << 2;                         // channel base 0..60
    const float* fbase = features + (size_t)b * NPTS * CCH;
    const int* ibase = idx + (size_t)b * NPTS;
    const int* cbase = counts + (size_t)b * R3;
    float* obase = out + (size_t)b * CCH * R3;
    int p0 = wave * PPW;

    int v = ibase[p0 + lane];                           // lane's own point's voxel
    float4 f[16];
    #pragma unroll
    for (int i = 0; i < 16; ++i)
        f[i] = *(const float4*)(fbase + (size_t)(p0 + i * 4 + sub) * CCH + cb);

    int v0 = __shfl(v, 0);
    if (__all(v == v0)) {
        float4 s = f[0];
        #pragma unroll
        for (int i = 1; i < 16; ++i) {
            s.x += f[i].x; s.y += f[i].y; s.z += f[i].z; s.w += f[i].w;
        }
        float r = 1.0f / (float)cbase[v0];
        s.x *= r; s.y *= r; s.z *= r; s.w *= r;
        s.x += __shfl_xor(s.x, 16); s.x += __shfl_xor(s.x, 32);
        s.y += __shfl_xor(s.y, 16); s.y += __shfl_xor(s.y, 32);
        s.z += __shfl_xor(s.z, 16); s.z += __shfl_xor(s.z, 32);
        s.w += __shfl_xor(s.w, 16); s.w += __shfl_xor(s.w, 32);
        if (sub == 0) {
            size_t o = (size_t)cb * R3 + v0;
            atomicAdd(&obase[o],          s.x);
            atomicAdd(&obase[o + R3],     s.y);
            atomicAdd(&obase[o + 2 * R3], s.z);
            atomicAdd(&obase[o + 3 * R3], s.w);
        }
    } else {
        // rare: per-register direct atomics
        #pragma unroll
        for (int i = 0; i < 16; ++i) {
            int vv = __shfl(v, i * 4 + sub);
            float r = 1.0f / (float)cbase[vv];
            size_t o = (size_t)cb * R3 + vv;
            atomicAdd(&obase[o],          f[i].x * r);
            atomicAdd(&obase[o + R3],     f[i].y * r);
            atomicAdd(&obase[o + 2 * R3], f[i].z * r);
            atomicAdd(&obase[o + 3 * R3], f[i].w * r);
        }
    }
}

extern "C" void kernel_launch(void* const* d_in, const int* in_sizes, int n_in,
                              void* d_out, int out_size, void* d_ws, size_t ws_size,
                              hipStream_t stream) {
    const float* features = (const float*)d_in[0];
    const float* coords   = (const float*)d_in[1];
    float* out = (float*)d_out;

    float* voxf = out;                                    // (B, C, R, R, R)
    float* nc   = out + (size_t)BATCH * CCH * R3;         // (B, N, 3)

    char* ws = (char*)d_ws;
    int*    counts   = (int*)ws;                          // B*R3 ints = 1 MiB
    int*    idx      = (int*)(ws + (1 << 20));            // B*NPTS ints = 1 MiB
    double* partials = (double*)(ws + (2 << 20));         // B*ABLK*3 doubles = 6 KiB
    float*  denom    = (float*)(ws + (2 << 20) + 8192);   // B floats

    dim3 agrid(ABLK + CZB, BATCH);
    stats_kernel<<<agrid, 256, 0, stream>>>(coords, partials, counts);
    denom_kernel<<<1, 64, 0, stream>>>(partials, denom);

    points_kernel<<<PBLK, 256, 0, stream>>>(coords, denom, nc, idx, counts, voxf);

    dim3 fgrid(FBLK, BATCH);
    feat_kernel<<<fgrid, 256, 0, stream>>>(features, idx, counts, voxf);
}